// Round 1
// 693.748 us; speedup vs baseline: 1.0471x; 1.0471x over previous
//
#include <hip/hip_runtime.h>
#include <hip/hip_bf16.h>

#define N_VAR 16
#define LAGS  16
#define HID   16
#define GRP   256        // N_VAR * N_VAR
#define BATCH 32768
#define WPAD  20         // padded LDS stride (shorts) per h-row: spreads banks

typedef __attribute__((ext_vector_type(8))) short  bf16x8;
typedef __attribute__((ext_vector_type(4))) short  short4v;
typedef __attribute__((ext_vector_type(4))) float  floatx4;

__device__ __forceinline__ float sigmoid_fast(float t) {
    float e = __expf(-t);                      // v_mul + v_exp_f32
    return __builtin_amdgcn_rcpf(1.0f + e);    // v_add + v_rcp_f32
}

__device__ __forceinline__ short f2bf(float f) {
    __hip_bfloat16 h = __float2bfloat16(f);    // RNE
    return __builtin_bit_cast(short, h);
}

// ---------------------------------------------------------------------------
// Prologue: cast W1 (mask folded in) and W2 to bf16 in d_ws.
//   W1b[g][h][l] = bf16(W1[g][h][l] * (causal[g][l] != 0))
//   W2b[g][k][h] = bf16(W2[g][k][h])
// ---------------------------------------------------------------------------
__global__ __launch_bounds__(256) void prep_weights(
    const float* __restrict__ W1, const float* __restrict__ W2,
    const int* __restrict__ causal,
    short* __restrict__ W1b, short* __restrict__ W2b)
{
    const int i = blockIdx.x * 256 + threadIdx.x;   // 0 .. 65535 = G*H*L
    const int g = i >> 8;
    const int l = i & 15;
    const float msk = (causal[g * LAGS + l] != 0) ? 1.0f : 0.0f;
    W1b[i] = f2bf(W1[i] * msk);
    W2b[i] = f2bf(W2[i]);
}

// ---------------------------------------------------------------------------
// Main: block = 4 waves, ALL with the same variable v (v = blockIdx & 15).
// Block covers 64 batch rows; wave widx owns rows b0 = bb*64 + widx*16.
// Per-v weights (W1b, W2b fragments + b1/b2/W3) staged into LDS once per
// block -> inner loop issues ONLY the x loads to the VMEM pipe.
// n-loop runs in even/odd pairs so both halves of each 128-B x line are
// requested together (no L1-thrash half-line refetch), with distance-1
// register prefetch and #pragma unroll 1 to keep VGPRs low.
// MFMA math identical to previous verified kernel:
//   mfma1: D1[h][m]  = W1m[g] . xm^T + b1[g]
//   mfma2: D2[ko][m] = W2[g] . h1^T  + b2[g]   (D1 frag IS B2 frag)
// ---------------------------------------------------------------------------
__global__ __launch_bounds__(256) void additive_mfma(
    const float* __restrict__ x,      // [B, G, L]
    const float* __restrict__ b1,     // [G, H]
    const float* __restrict__ b2,     // [G, H]
    const float* __restrict__ W3,     // [N, N*H]
    const float* __restrict__ b3,     // [N]
    const short* __restrict__ W1b,    // [G, H, L] bf16, masked
    const short* __restrict__ W2b,    // [G, H, H] bf16
    float* __restrict__ out)          // [B, N]
{
    __shared__ short w1s[16][16][WPAD];   // [n][h][l]   10240 B
    __shared__ short w2s[16][16][WPAD];   // [n][ko][h]  10240 B
    __shared__ float b1s[16][16];         // [n][h]       1024 B
    __shared__ float b2s[16][16];         // [n][ko]      1024 B
    __shared__ float w3s[16][16];         // [n][ko]      1024 B

    const int t    = threadIdx.x;
    const int v    = blockIdx.x & (N_VAR - 1);
    const int bb   = blockIdx.x >> 4;
    const int widx = t >> 6;
    const int lane = t & 63;
    const int m    = lane & 15;              // batch-row / fragment row index
    const int q    = lane >> 4;              // quad
    const int b0   = bb * 64 + widx * 16;

    // ---- stage this v's weights into LDS (once per block) ----
    {
        const int n  = t >> 4;
        const int hh = t & 15;
        const short* s1 = W1b + (((v * N_VAR + n) * HID) + hh) * LAGS;
        const short* s2 = W2b + (((v * N_VAR + n) * HID) + hh) * HID;
        #pragma unroll
        for (int j = 0; j < 4; ++j) {
            *reinterpret_cast<short4v*>(&w1s[n][hh][j * 4]) =
                *reinterpret_cast<const short4v*>(s1 + j * 4);
            *reinterpret_cast<short4v*>(&w2s[n][hh][j * 4]) =
                *reinterpret_cast<const short4v*>(s2 + j * 4);
        }
        (&b1s[0][0])[t] = b1[v * GRP + t];       // b1[(v*16+n)*16 + h]
        (&b2s[0][0])[t] = b2[v * GRP + t];
        (&w3s[0][0])[t] = W3[v * (N_VAR * HID) + t];
    }
    __syncthreads();

    const float* __restrict__ xp =
        x + (size_t)(b0 + m) * (GRP * LAGS) + v * (N_VAR * LAGS) + q * 4;
    const float b3v = b3[v];
    float acc = 0.0f;

    const short* w1p = &w1s[0][m][q * 4];    // + n*16*WPAD
    const short* w2p = &w2s[0][m][q * 4];
    const float* b1p = &b1s[0][q * 4];       // + n*16
    const float* b2p = &b2s[0][q * 4];
    const float* w3p = &w3s[0][q * 4];

    auto process = [&](int n, floatx4 xv) {
        const short4v w1v = *reinterpret_cast<const short4v*>(w1p + n * (16 * WPAD));
        bf16x8 fa1 = {w1v[0], w1v[1], w1v[2], w1v[3],
                      (short)0, (short)0, (short)0, (short)0};
        bf16x8 fx  = {f2bf(xv[0]), f2bf(xv[1]), f2bf(xv[2]), f2bf(xv[3]),
                      (short)0, (short)0, (short)0, (short)0};
        floatx4 c1 = *reinterpret_cast<const floatx4*>(b1p + n * 16);
        floatx4 d1 = __builtin_amdgcn_mfma_f32_16x16x32_bf16(fa1, fx, c1, 0, 0, 0);

        bf16x8 fb2 = {f2bf(sigmoid_fast(d1[0])), f2bf(sigmoid_fast(d1[1])),
                      f2bf(sigmoid_fast(d1[2])), f2bf(sigmoid_fast(d1[3])),
                      (short)0, (short)0, (short)0, (short)0};
        const short4v w2v = *reinterpret_cast<const short4v*>(w2p + n * (16 * WPAD));
        bf16x8 fa2 = {w2v[0], w2v[1], w2v[2], w2v[3],
                      (short)0, (short)0, (short)0, (short)0};
        floatx4 c2 = *reinterpret_cast<const floatx4*>(b2p + n * 16);
        floatx4 d2 = __builtin_amdgcn_mfma_f32_16x16x32_bf16(fa2, fb2, c2, 0, 0, 0);

        const floatx4 w3v = *reinterpret_cast<const floatx4*>(w3p + n * 16);
        acc += sigmoid_fast(d2[0]) * w3v[0];
        acc += sigmoid_fast(d2[1]) * w3v[1];
        acc += sigmoid_fast(d2[2]) * w3v[2];
        acc += sigmoid_fast(d2[3]) * w3v[3];
    };

    // even/odd g-pairs: both halves of each 128-B x line requested together
    floatx4 cur0 = *reinterpret_cast<const floatx4*>(xp);
    floatx4 cur1 = *reinterpret_cast<const floatx4*>(xp + LAGS);

    #pragma unroll 1
    for (int np = 0; np < 8; ++np) {
        floatx4 nxt0, nxt1;
        if (np < 7) {
            nxt0 = *reinterpret_cast<const floatx4*>(xp + (2 * np + 2) * LAGS);
            nxt1 = *reinterpret_cast<const floatx4*>(xp + (2 * np + 3) * LAGS);
        }
        process(2 * np,     cur0);
        process(2 * np + 1, cur1);
        if (np < 7) { cur0 = nxt0; cur1 = nxt1; }
    }

    // reduce over the 4 quads holding the same batch row m
    acc += __shfl_xor(acc, 16);
    acc += __shfl_xor(acc, 32);
    if (lane < 16)
        out[(size_t)(b0 + lane) * N_VAR + v] = acc + b3v;
}

extern "C" void kernel_launch(void* const* d_in, const int* in_sizes, int n_in,
                              void* d_out, int out_size, void* d_ws, size_t ws_size,
                              hipStream_t stream) {
    const float* x      = (const float*)d_in[0];
    const int*   causal = (const int*)  d_in[1];
    const float* W1     = (const float*)d_in[2];
    const float* b1     = (const float*)d_in[3];
    const float* W2     = (const float*)d_in[4];
    const float* b2     = (const float*)d_in[5];
    const float* W3     = (const float*)d_in[6];
    const float* b3     = (const float*)d_in[7];
    float* out          = (float*)d_out;

    short* W1b = (short*)d_ws;                        // 128 KB
    short* W2b = (short*)d_ws + GRP * HID * LAGS;     // next 128 KB

    prep_weights<<<(GRP * HID * LAGS) / 256, 256, 0, stream>>>(
        W1, W2, causal, W1b, W2b);

    const int n_blocks = (BATCH / 64) * N_VAR;        // 8192 blocks, 4 waves each
    additive_mfma<<<n_blocks, 256, 0, stream>>>(
        x, b1, b2, W3, b3, W1b, W2b, out);
}

// Round 2
// 677.120 us; speedup vs baseline: 1.0728x; 1.0246x over previous
//
#include <hip/hip_runtime.h>
#include <hip/hip_bf16.h>

#define N_VAR 16
#define LAGS  16
#define HID   16
#define GRP   256        // N_VAR * N_VAR
#define BATCH 32768
#define WPAD  20         // padded LDS stride (shorts) per h-row (8B-aligned rows)

typedef __attribute__((ext_vector_type(8))) short  bf16x8;
typedef __attribute__((ext_vector_type(4))) short  short4v;
typedef __attribute__((ext_vector_type(4))) float  floatx4;

__device__ __forceinline__ float sigmoid_fast(float t) {
    float e = __expf(-t);                      // v_mul + v_exp_f32
    return __builtin_amdgcn_rcpf(1.0f + e);    // v_add + v_rcp_f32
}

__device__ __forceinline__ short f2bf(float f) {
    __hip_bfloat16 h = __float2bfloat16(f);    // RNE
    return __builtin_bit_cast(short, h);
}

// ---------------------------------------------------------------------------
// Prologue: cast W1 (mask folded in) and W2 to bf16 in d_ws.
// ---------------------------------------------------------------------------
__global__ __launch_bounds__(256) void prep_weights(
    const float* __restrict__ W1, const float* __restrict__ W2,
    const int* __restrict__ causal,
    short* __restrict__ W1b, short* __restrict__ W2b)
{
    const int i = blockIdx.x * 256 + threadIdx.x;   // 0 .. 65535 = G*H*L
    const int g = i >> 8;
    const int l = i & 15;
    const float msk = (causal[g * LAGS + l] != 0) ? 1.0f : 0.0f;
    W1b[i] = f2bf(W1[i] * msk);
    W2b[i] = f2bf(W2[i]);
}

// ---------------------------------------------------------------------------
// Main: block = 4 waves, same v, 64 batch rows. All global x reads are now
// COOPERATIVE + CONTIGUOUS (512-B segments per instruction), staged through a
// bank-rotated bf16 LDS tile; the batch-rows-across-lanes transpose that the
// MFMA B-fragment needs happens via ds_read_b64, not a 16-KB-stride gather.
// Two g-halves of 8 groups each keep LDS at 16 KB (x) + 23.5 KB (weights)
// = 39.9 KB -> 4 blocks/CU; stage/compute phases of different blocks overlap.
// LDS rotation: 8-B unit u of row i stored at (u + 4*i) & 31 — bijective,
// uniform 4 slots/bank on both write (lane-linear) and fragment read (4m+q).
// MFMA math identical to previous verified kernels (bit-identical results).
// ---------------------------------------------------------------------------
__global__ __launch_bounds__(256, 4) void additive_mfma(
    const float* __restrict__ x,      // [B, G, L]
    const float* __restrict__ b1,     // [G, H]
    const float* __restrict__ b2,     // [G, H]
    const float* __restrict__ W3,     // [N, N*H]
    const float* __restrict__ b3,     // [N]
    const short* __restrict__ W1b,    // [G, H, L] bf16, masked
    const short* __restrict__ W2b,    // [G, H, H] bf16
    float* __restrict__ out)          // [B, N]
{
    __shared__ short xs[64 * 128];        // 16 KB: 64 rows x 8 groups x 16 bf16
    __shared__ short w1s[16][16][WPAD];   // [n][h][l]   10240 B
    __shared__ short w2s[16][16][WPAD];   // [n][ko][h]  10240 B
    __shared__ float b1s[16][16];         // 1024 B
    __shared__ float b2s[16][16];         // 1024 B
    __shared__ float w3s[16][16];         // 1024 B

    const int t    = threadIdx.x;
    const int v    = blockIdx.x & (N_VAR - 1);
    const int bb   = blockIdx.x >> 4;
    const int widx = t >> 6;
    const int lane = t & 63;
    const int m    = lane & 15;              // batch-row within fragment
    const int q    = lane >> 4;              // quad
    const int row  = (widx << 4) + m;        // block-local batch row 0..63
    const int b0   = (bb << 6) + (widx << 4);

    // ---- stage this v's weights into LDS (once per block) ----
    {
        const int n  = t >> 4;
        const int hh = t & 15;
        const short* s1 = W1b + (((v * N_VAR + n) * HID) + hh) * LAGS;
        const short* s2 = W2b + (((v * N_VAR + n) * HID) + hh) * HID;
        #pragma unroll
        for (int j = 0; j < 4; ++j) {
            *reinterpret_cast<short4v*>(&w1s[n][hh][j * 4]) =
                *reinterpret_cast<const short4v*>(s1 + j * 4);
            *reinterpret_cast<short4v*>(&w2s[n][hh][j * 4]) =
                *reinterpret_cast<const short4v*>(s2 + j * 4);
        }
        (&b1s[0][0])[t] = b1[v * GRP + t];
        (&b2s[0][0])[t] = b2[v * GRP + t];
        (&w3s[0][0])[t] = W3[v * (N_VAR * HID) + t];
    }

    const float b3v = b3[v];
    float acc = 0.0f;

    const short* w1p = &w1s[0][m][q * 4];    // + n*16*WPAD
    const short* w2p = &w2s[0][m][q * 4];
    const float* b1p = &b1s[0][q * 4];       // + n*16
    const float* b2p = &b2s[0][q * 4];
    const float* w3p = &w3s[0][q * 4];

    const float* __restrict__ xgbase =
        x + (size_t)(bb * 64) * (GRP * LAGS) + v * (N_VAR * LAGS);

    for (int half = 0; half < 2; ++half) {
        // ---- stage x: 64 rows x 8 groups, 32 KB f32 -> 16 KB bf16 LDS ----
        // flat unit u = p*256 + t: row i = u>>5, dwordx4-unit c = u&31.
        // Each wave-instruction covers two 512-B contiguous segments.
        #pragma unroll
        for (int p = 0; p < 8; ++p) {
            const int u = (p << 8) + t;
            const int i = u >> 5;
            const int c = u & 31;
            const floatx4 f = *reinterpret_cast<const floatx4*>(
                xgbase + (size_t)i * (GRP * LAGS) + (half * 8) * LAGS + c * 4);
            short4v s = {f2bf(f[0]), f2bf(f[1]), f2bf(f[2]), f2bf(f[3])};
            *reinterpret_cast<short4v*>(
                &xs[(i << 7) + (((c + (i << 2)) & 31) << 2)]) = s;
        }
        __syncthreads();

        #pragma unroll 2
        for (int nl = 0; nl < 8; ++nl) {
            const int n = (half << 3) + nl;

            // B1 fragment from rotated LDS tile (conflict-free ds_read_b64)
            const short4v xv = *reinterpret_cast<const short4v*>(
                &xs[(row << 7) + ((((nl << 2) + q + (row << 2)) & 31) << 2)]);
            bf16x8 fx = {xv[0], xv[1], xv[2], xv[3],
                         (short)0, (short)0, (short)0, (short)0};

            const short4v w1v = *reinterpret_cast<const short4v*>(
                w1p + n * (16 * WPAD));
            bf16x8 fa1 = {w1v[0], w1v[1], w1v[2], w1v[3],
                          (short)0, (short)0, (short)0, (short)0};
            floatx4 c1 = *reinterpret_cast<const floatx4*>(b1p + n * 16);
            floatx4 d1 = __builtin_amdgcn_mfma_f32_16x16x32_bf16(fa1, fx, c1, 0, 0, 0);

            bf16x8 fb2 = {f2bf(sigmoid_fast(d1[0])), f2bf(sigmoid_fast(d1[1])),
                          f2bf(sigmoid_fast(d1[2])), f2bf(sigmoid_fast(d1[3])),
                          (short)0, (short)0, (short)0, (short)0};
            const short4v w2v = *reinterpret_cast<const short4v*>(
                w2p + n * (16 * WPAD));
            bf16x8 fa2 = {w2v[0], w2v[1], w2v[2], w2v[3],
                          (short)0, (short)0, (short)0, (short)0};
            floatx4 c2 = *reinterpret_cast<const floatx4*>(b2p + n * 16);
            floatx4 d2 = __builtin_amdgcn_mfma_f32_16x16x32_bf16(fa2, fb2, c2, 0, 0, 0);

            const floatx4 w3v = *reinterpret_cast<const floatx4*>(w3p + n * 16);
            acc += sigmoid_fast(d2[0]) * w3v[0];
            acc += sigmoid_fast(d2[1]) * w3v[1];
            acc += sigmoid_fast(d2[2]) * w3v[2];
            acc += sigmoid_fast(d2[3]) * w3v[3];
        }
        __syncthreads();   // protect xs before next half's staging
    }

    // reduce over the 4 quads holding the same batch row m
    acc += __shfl_xor(acc, 16);
    acc += __shfl_xor(acc, 32);
    if (lane < 16)
        out[(size_t)(b0 + lane) * N_VAR + v] = acc + b3v;
}

extern "C" void kernel_launch(void* const* d_in, const int* in_sizes, int n_in,
                              void* d_out, int out_size, void* d_ws, size_t ws_size,
                              hipStream_t stream) {
    const float* x      = (const float*)d_in[0];
    const int*   causal = (const int*)  d_in[1];
    const float* W1     = (const float*)d_in[2];
    const float* b1     = (const float*)d_in[3];
    const float* W2     = (const float*)d_in[4];
    const float* b2     = (const float*)d_in[5];
    const float* W3     = (const float*)d_in[6];
    const float* b3     = (const float*)d_in[7];
    float* out          = (float*)d_out;

    short* W1b = (short*)d_ws;                        // 128 KB
    short* W2b = (short*)d_ws + GRP * HID * LAGS;     // next 128 KB

    prep_weights<<<(GRP * HID * LAGS) / 256, 256, 0, stream>>>(
        W1, W2, causal, W1b, W2b);

    const int n_blocks = (BATCH / 64) * N_VAR;        // 8192 blocks, 4 waves each
    additive_mfma<<<n_blocks, 256, 0, stream>>>(
        x, b1, b2, W3, b3, W1b, W2b, out);
}